// Round 1
// baseline (904.611 us; speedup 1.0000x reference)
//
#include <hip/hip_runtime.h>
#include <hip/hip_bf16.h>
#include <stdint.h>

// ---------- bf16 helpers (raw ushort representation) ----------
__device__ inline float bf2f(ushort u) {
    union { uint32_t u; float f; } v; v.u = ((uint32_t)u) << 16; return v.f;
}
__device__ inline ushort f2bf(float f) {
    union { float f; uint32_t u; } v; v.f = f;
    uint32_t u = v.u;
    uint32_t r = (u + 0x7fffu + ((u >> 16) & 1u)) >> 16;  // RNE
    return (ushort)r;
}
__device__ inline uint32_t pk2bf(uint32_t flo, uint32_t fhi) {  // two f32 bit-patterns -> packed bf16x2
    uint32_t lo = (flo + 0x7fffu + ((flo >> 16) & 1u)) >> 16;
    uint32_t hi = (fhi + 0x7fffu + ((fhi >> 16) & 1u)) >> 16;
    return lo | (hi << 16);
}

typedef __attribute__((ext_vector_type(8))) short bf16x8;
typedef __attribute__((ext_vector_type(4))) float f32x4;

// async global->LDS, 16B per lane; LDS dest must be wave-uniform base (HW adds lane*16)
__device__ inline void gload_lds16(const ushort* g, ushort* l) {
    __builtin_amdgcn_global_load_lds(
        (const __attribute__((address_space(1))) void*)g,
        (__attribute__((address_space(3))) void*)l, 16, 0, 0);
}

// ---------- weight transpose+cast: W[1024,1024] f32 -> Wt[1024,1024] bf16 ----------
__global__ void transpose1024(const float* __restrict__ Wq, const float* __restrict__ Wk,
                              const float* __restrict__ Wv, const float* __restrict__ Wo,
                              ushort* __restrict__ WqT, ushort* __restrict__ WkT,
                              ushort* __restrict__ WvT, ushort* __restrict__ WoT) {
    const float* in; ushort* out;
    switch (blockIdx.z) {
        case 0: in = Wq; out = WqT; break;
        case 1: in = Wk; out = WkT; break;
        case 2: in = Wv; out = WvT; break;
        default: in = Wo; out = WoT; break;
    }
    __shared__ ushort tile[64][65];
    const int t = threadIdx.x;
    const int c = t & 63, rq = t >> 6;
    const int bx = blockIdx.x * 64, by = blockIdx.y * 64;
#pragma unroll
    for (int i = 0; i < 16; ++i) {
        int r = i * 4 + rq;
        tile[r][c] = f2bf(in[(size_t)(by + r) * 1024 + bx + c]);
    }
    __syncthreads();
#pragma unroll
    for (int i = 0; i < 16; ++i) {
        int r = i * 4 + rq;
        out[(size_t)(bx + r) * 1024 + by + c] = tile[c][r];
    }
}

// ---------- x chunk cast: f32 -> bf16, 8 elems/thread, grid-stride ----------
__global__ __launch_bounds__(256)
void cast_bf16(const float* __restrict__ in, ushort* __restrict__ out, size_t n8) {
    size_t i = (size_t)blockIdx.x * blockDim.x + threadIdx.x;
    const size_t stride = (size_t)gridDim.x * blockDim.x;
    for (; i < n8; i += stride) {
        const uint4 lo = *(const uint4*)&in[i * 8];
        const uint4 hi = *(const uint4*)&in[i * 8 + 4];
        uint4 o;
        o.x = pk2bf(lo.x, lo.y); o.y = pk2bf(lo.z, lo.w);
        o.z = pk2bf(hi.x, hi.y); o.w = pk2bf(hi.z, hi.w);
        *(uint4*)&out[i * 8] = o;
    }
}

// ---------- bf16-MFMA GEMM: C[M,N] = A[M,K] @ Bt[N,K]^T ----------
// m97 structure: 128x128 tile, BK=64, 4 waves 2x2, 16x16x32 MFMA, 4x4 acc/wave.
// global_load_lds width=16 staging into LINEAR (unpadded) LDS, 2-barrier K-loop.
template <bool C_F32>
__global__ __launch_bounds__(256)
void gemm_bt(const ushort* __restrict__ A, const ushort* __restrict__ Bt,
             void* __restrict__ C_, int M, int N, int K) {
    __shared__ __attribute__((aligned(16))) ushort As[128 * 64];
    __shared__ __attribute__((aligned(16))) ushort Bs[128 * 64];
    const int t = threadIdx.x;
    const int lane = t & 63, wave = t >> 6;
    const int wm = wave >> 1, wn = wave & 1;
    const int quad = lane >> 4, l16 = lane & 15;
    const int m0 = blockIdx.y * 128, n0 = blockIdx.x * 128;

    const f32x4 zero = {0.f, 0.f, 0.f, 0.f};
    f32x4 acc[4][4];
#pragma unroll
    for (int i = 0; i < 4; ++i)
#pragma unroll
        for (int j = 0; j < 4; ++j) acc[i][j] = zero;

    for (int k0 = 0; k0 < K; k0 += 64) {
        __syncthreads();                       // prev iter's LDS reads done
#pragma unroll
        for (int c = 0; c < 4; ++c) {
            // granule gi in [0,1024): row r = gi>>3 (128 rows), col granule g = gi&7 (8 x 16B/row)
            const int gi = (c * 4 + wave) * 64 + lane;
            const int r = gi >> 3, g = (gi & 7) * 8;
            gload_lds16(&A [(size_t)(m0 + r) * K + k0 + g], &As[(size_t)(c * 4 + wave) * 512]);
            gload_lds16(&Bt[(size_t)(n0 + r) * K + k0 + g], &Bs[(size_t)(c * 4 + wave) * 512]);
        }
        __syncthreads();                       // compiler drains vmcnt(0) before barrier
#pragma unroll
        for (int ks = 0; ks < 2; ++ks) {
            bf16x8 af[4], bfr[4];
            const int gk = ks * 4 + quad;      // A[m][k]: m=lane&15, k=quad*8+j
#pragma unroll
            for (int mt = 0; mt < 4; ++mt) {
                const int r = wm * 64 + mt * 16 + l16;
                af[mt] = *(const bf16x8*)&As[r * 64 + gk * 8];
            }
#pragma unroll
            for (int nt = 0; nt < 4; ++nt) {
                const int r = wn * 64 + nt * 16 + l16;
                bfr[nt] = *(const bf16x8*)&Bs[r * 64 + gk * 8];
            }
#pragma unroll
            for (int mt = 0; mt < 4; ++mt)
#pragma unroll
                for (int nt = 0; nt < 4; ++nt)
                    acc[mt][nt] = __builtin_amdgcn_mfma_f32_16x16x32_bf16(
                        af[mt], bfr[nt], acc[mt][nt], 0, 0, 0);
        }
    }
    // C/D layout: col = lane&15, row = quad*4 + reg  [m89/m91 verified]
#pragma unroll
    for (int mt = 0; mt < 4; ++mt)
#pragma unroll
        for (int nt = 0; nt < 4; ++nt)
#pragma unroll
            for (int r4 = 0; r4 < 4; ++r4) {
                const int row = m0 + wm * 64 + mt * 16 + quad * 4 + r4;
                const int col = n0 + wn * 64 + nt * 16 + l16;
                if (C_F32) ((float*)C_)[(size_t)row * N + col] = acc[mt][nt][r4];
                else       ((ushort*)C_)[(size_t)row * N + col] = f2bf(acc[mt][nt][r4]);
            }
}

// ---------- attention: per (b,h) 64x64 tile, VALU f32, bias f32 ----------
// UNCHANGED from verified baseline (control group for per-dispatch attribution).
#define PADQ 72
__global__ __launch_bounds__(256)
void attn64(const ushort* __restrict__ Q, const ushort* __restrict__ K,
            const ushort* __restrict__ V, const float* __restrict__ bias,
            ushort* __restrict__ O) {
    __shared__ __attribute__((aligned(16))) ushort Qs[64 * PADQ];
    __shared__ __attribute__((aligned(16))) ushort Ks[64 * PADQ];
    __shared__ __attribute__((aligned(16))) ushort Vs[64 * PADQ];
    __shared__ float S[64 * 65];
    __shared__ float rmax_[64], rinv_[64];
    const int t = threadIdx.x;
    const int b = blockIdx.x >> 4, h = blockIdx.x & 15;
    const size_t base = (size_t)b * 64 * 1024 + (size_t)h * 64;

#pragma unroll
    for (int i = 0; i < 2; ++i) {
        int slot = t + i * 256;
        int r = slot >> 3, g = slot & 7;
        size_t go = base + (size_t)r * 1024 + (size_t)g * 8;
        *(uint4*)&Qs[r * PADQ + g * 8] = *(const uint4*)&Q[go];
        *(uint4*)&Ks[r * PADQ + g * 8] = *(const uint4*)&K[go];
        *(uint4*)&Vs[r * PADQ + g * 8] = *(const uint4*)&V[go];
    }
    __syncthreads();

    const int ti = t >> 4, tj = t & 15;
    const int i0 = ti * 4, j0 = tj * 4;
    // S = Q K^T / 8 + bias
    float acc[4][4] = {};
    for (int d = 0; d < 64; d += 2) {
        float q[4][2], k[4][2];
#pragma unroll
        for (int a = 0; a < 4; ++a) {
            q[a][0] = bf2f(Qs[(i0 + a) * PADQ + d]);
            q[a][1] = bf2f(Qs[(i0 + a) * PADQ + d + 1]);
            k[a][0] = bf2f(Ks[(j0 + a) * PADQ + d]);
            k[a][1] = bf2f(Ks[(j0 + a) * PADQ + d + 1]);
        }
#pragma unroll
        for (int a = 0; a < 4; ++a)
#pragma unroll
            for (int bb = 0; bb < 4; ++bb)
                acc[a][bb] += q[a][0] * k[bb][0] + q[a][1] * k[bb][1];
    }
#pragma unroll
    for (int a = 0; a < 4; ++a)
#pragma unroll
        for (int bb = 0; bb < 4; ++bb)
            S[(i0 + a) * 65 + j0 + bb] =
                acc[a][bb] * 0.125f + bias[(h * 64 + i0 + a) * 64 + j0 + bb];
    __syncthreads();

    if (t < 64) {
        float m = -1e30f;
        for (int j = 0; j < 64; ++j) m = fmaxf(m, S[t * 65 + j]);
        float s = 0.f;
        for (int j = 0; j < 64; ++j) s += __expf(S[t * 65 + j] - m);
        rmax_[t] = m; rinv_[t] = 1.f / s;
    }
    __syncthreads();
#pragma unroll
    for (int a = 0; a < 4; ++a)
#pragma unroll
        for (int bb = 0; bb < 4; ++bb) {
            int i = i0 + a, j = j0 + bb;
            S[i * 65 + j] = __expf(S[i * 65 + j] - rmax_[i]) * rinv_[i];
        }
    __syncthreads();

    // O = P V : thread owns rows i0..i0+3, out cols d0..d0+3
    const int d0 = tj * 4;
    float o[4][4] = {};
    for (int j = 0; j < 64; ++j) {
        ushort4 vr = *(const ushort4*)&Vs[j * PADQ + d0];
        float v0 = bf2f(vr.x), v1 = bf2f(vr.y), v2 = bf2f(vr.z), v3 = bf2f(vr.w);
#pragma unroll
        for (int a = 0; a < 4; ++a) {
            float p = S[(i0 + a) * 65 + j];
            o[a][0] += p * v0; o[a][1] += p * v1; o[a][2] += p * v2; o[a][3] += p * v3;
        }
    }
#pragma unroll
    for (int a = 0; a < 4; ++a) {
        ushort4 pk;
        pk.x = f2bf(o[a][0]); pk.y = f2bf(o[a][1]);
        pk.z = f2bf(o[a][2]); pk.w = f2bf(o[a][3]);
        *(ushort4*)&O[base + (size_t)(i0 + a) * 1024 + d0] = pk;  // in-place over Q region
    }
}

extern "C" void kernel_launch(void* const* d_in, const int* in_sizes, int n_in,
                              void* d_out, int out_size, void* d_ws, size_t ws_size,
                              hipStream_t stream) {
    const float* x    = (const float*)d_in[0];   // [512,64,1024] f32
    const float* bias = (const float*)d_in[1];   // [1,16,64,64]  f32
    const float* Wq   = (const float*)d_in[2];
    const float* Wk   = (const float*)d_in[3];
    const float* Wv   = (const float*)d_in[4];
    const float* Wo   = (const float*)d_in[5];
    float* out = (float*)d_out;                  // [512,64,1024] f32

    const size_t D = 1024;
    const int CHUNK_B = 128;               // batches per chunk
    const int NCHUNK  = 512 / CHUNK_B;     // 4
    const size_t CROWS = (size_t)CHUNK_B * 64;   // 8192 rows per chunk
    const size_t CELEM = CROWS * D;              // 8.39M elements

    // ws layout (58.7 MB): 4 transposed bf16 weights (8.4 MB) + bf16 Q/K/V chunk bufs.
    // bf16 x-chunk (16.8 MB) lives in the chunk's own (not-yet-written) d_out region.
    ushort* WqT = (ushort*)d_ws;
    ushort* WkT = WqT + D * D;
    ushort* WvT = WkT + D * D;
    ushort* WoT = WvT + D * D;
    ushort* Qc  = WoT + D * D;             // 16.8 MB
    ushort* Kc  = Qc + CELEM;              // 16.8 MB
    ushort* Vc  = Kc + CELEM;              // 16.8 MB

    transpose1024<<<dim3(16, 16, 4), 256, 0, stream>>>(Wq, Wk, Wv, Wo, WqT, WkT, WvT, WoT);

    for (int c = 0; c < NCHUNK; ++c) {
        const float* xc = x + (size_t)c * CELEM;
        float* outc = out + (size_t)c * CELEM;
        ushort* Xc = (ushort*)outc;        // scratch: overwritten by final GEMM below
        cast_bf16<<<2048, 256, 0, stream>>>(xc, Xc, CELEM / 8);
        gemm_bt<false><<<dim3(8, 64), 256, 0, stream>>>(Xc, WqT, Qc, (int)CROWS, 1024, 1024);
        gemm_bt<false><<<dim3(8, 64), 256, 0, stream>>>(Xc, WkT, Kc, (int)CROWS, 1024, 1024);
        gemm_bt<false><<<dim3(8, 64), 256, 0, stream>>>(Xc, WvT, Vc, (int)CROWS, 1024, 1024);
        attn64<<<CHUNK_B * 16, 256, 0, stream>>>(Qc, Kc, Vc, bias, Qc);
        gemm_bt<true><<<dim3(8, 64), 256, 0, stream>>>(Qc, WoT, outc, (int)CROWS, 1024, 1024);
    }
}

// Round 2
// 759.175 us; speedup vs baseline: 1.1916x; 1.1916x over previous
//
#include <hip/hip_runtime.h>
#include <hip/hip_bf16.h>
#include <stdint.h>

// ---------- bf16 helpers (raw ushort representation) ----------
__device__ inline float bf2f(ushort u) {
    union { uint32_t u; float f; } v; v.u = ((uint32_t)u) << 16; return v.f;
}
__device__ inline ushort f2bf(float f) {
    union { float f; uint32_t u; } v; v.f = f;
    uint32_t u = v.u;
    uint32_t r = (u + 0x7fffu + ((u >> 16) & 1u)) >> 16;  // RNE
    return (ushort)r;
}
__device__ inline uint32_t pk2bf(uint32_t flo, uint32_t fhi) {  // two f32 bit-patterns -> packed bf16x2
    uint32_t lo = (flo + 0x7fffu + ((flo >> 16) & 1u)) >> 16;
    uint32_t hi = (fhi + 0x7fffu + ((fhi >> 16) & 1u)) >> 16;
    return lo | (hi << 16);
}

typedef __attribute__((ext_vector_type(8))) short bf16x8;
typedef __attribute__((ext_vector_type(4))) float f32x4;

// async global->LDS, 16B per lane; LDS dest must be wave-uniform base (HW adds lane*16)
__device__ inline void gload_lds16(const ushort* g, ushort* l) {
    __builtin_amdgcn_global_load_lds(
        (const __attribute__((address_space(1))) void*)g,
        (__attribute__((address_space(3))) void*)l, 16, 0, 0);
}

// ---------- weight transpose+cast: W[1024,1024] f32 -> Wt[1024,1024] bf16 ----------
__global__ void transpose1024(const float* __restrict__ Wq, const float* __restrict__ Wk,
                              const float* __restrict__ Wv, const float* __restrict__ Wo,
                              ushort* __restrict__ WqT, ushort* __restrict__ WkT,
                              ushort* __restrict__ WvT, ushort* __restrict__ WoT) {
    const float* in; ushort* out;
    switch (blockIdx.z) {
        case 0: in = Wq; out = WqT; break;
        case 1: in = Wk; out = WkT; break;
        case 2: in = Wv; out = WvT; break;
        default: in = Wo; out = WoT; break;
    }
    __shared__ ushort tile[64][65];
    const int t = threadIdx.x;
    const int c = t & 63, rq = t >> 6;
    const int bx = blockIdx.x * 64, by = blockIdx.y * 64;
#pragma unroll
    for (int i = 0; i < 16; ++i) {
        int r = i * 4 + rq;
        tile[r][c] = f2bf(in[(size_t)(by + r) * 1024 + bx + c]);
    }
    __syncthreads();
#pragma unroll
    for (int i = 0; i < 16; ++i) {
        int r = i * 4 + rq;
        out[(size_t)(bx + r) * 1024 + by + c] = tile[c][r];
    }
}

// ---------- x chunk cast: f32 -> bf16, 8 elems/thread, grid-stride ----------
__global__ __launch_bounds__(256)
void cast_bf16(const float* __restrict__ in, ushort* __restrict__ out, size_t n8) {
    size_t i = (size_t)blockIdx.x * blockDim.x + threadIdx.x;
    const size_t stride = (size_t)gridDim.x * blockDim.x;
    for (; i < n8; i += stride) {
        const uint4 lo = *(const uint4*)&in[i * 8];
        const uint4 hi = *(const uint4*)&in[i * 8 + 4];
        uint4 o;
        o.x = pk2bf(lo.x, lo.y); o.y = pk2bf(lo.z, lo.w);
        o.z = pk2bf(hi.x, hi.y); o.w = pk2bf(hi.z, hi.w);
        *(uint4*)&out[i * 8] = o;
    }
}

// ---------- bf16-MFMA GEMM: C[M,N] = A[M,K] @ Bt[N,K]^T ----------
// m97 structure: 128x128 tile, BK=64, 4 waves 2x2, 16x16x32 MFMA, 4x4 acc/wave.
// global_load_lds width=16 staging into LINEAR (unpadded) LDS, 2-barrier K-loop.
// A has row stride lda (elements); Bt row stride is K.
template <bool C_F32>
__global__ __launch_bounds__(256)
void gemm_bt(const ushort* __restrict__ A, int lda, const ushort* __restrict__ Bt,
             void* __restrict__ C_, int M, int N, int K) {
    __shared__ __attribute__((aligned(16))) ushort As[128 * 64];
    __shared__ __attribute__((aligned(16))) ushort Bs[128 * 64];
    const int t = threadIdx.x;
    const int lane = t & 63, wave = t >> 6;
    const int wm = wave >> 1, wn = wave & 1;
    const int quad = lane >> 4, l16 = lane & 15;
    const int m0 = blockIdx.y * 128, n0 = blockIdx.x * 128;

    const f32x4 zero = {0.f, 0.f, 0.f, 0.f};
    f32x4 acc[4][4];
#pragma unroll
    for (int i = 0; i < 4; ++i)
#pragma unroll
        for (int j = 0; j < 4; ++j) acc[i][j] = zero;

    for (int k0 = 0; k0 < K; k0 += 64) {
        __syncthreads();                       // prev iter's LDS reads done
#pragma unroll
        for (int c = 0; c < 4; ++c) {
            const int gi = (c * 4 + wave) * 64 + lane;
            const int r = gi >> 3, g = (gi & 7) * 8;
            gload_lds16(&A [(size_t)(m0 + r) * lda + k0 + g], &As[(size_t)(c * 4 + wave) * 512]);
            gload_lds16(&Bt[(size_t)(n0 + r) * K   + k0 + g], &Bs[(size_t)(c * 4 + wave) * 512]);
        }
        __syncthreads();                       // compiler drains vmcnt(0) before barrier
#pragma unroll
        for (int ks = 0; ks < 2; ++ks) {
            bf16x8 af[4], bfr[4];
            const int gk = ks * 4 + quad;      // A[m][k]: m=lane&15, k=quad*8+j
#pragma unroll
            for (int mt = 0; mt < 4; ++mt) {
                const int r = wm * 64 + mt * 16 + l16;
                af[mt] = *(const bf16x8*)&As[r * 64 + gk * 8];
            }
#pragma unroll
            for (int nt = 0; nt < 4; ++nt) {
                const int r = wn * 64 + nt * 16 + l16;
                bfr[nt] = *(const bf16x8*)&Bs[r * 64 + gk * 8];
            }
#pragma unroll
            for (int mt = 0; mt < 4; ++mt)
#pragma unroll
                for (int nt = 0; nt < 4; ++nt)
                    acc[mt][nt] = __builtin_amdgcn_mfma_f32_16x16x32_bf16(
                        af[mt], bfr[nt], acc[mt][nt], 0, 0, 0);
        }
    }
    // C/D layout: col = lane&15, row = quad*4 + reg  [m89/m91 verified]
#pragma unroll
    for (int mt = 0; mt < 4; ++mt)
#pragma unroll
        for (int nt = 0; nt < 4; ++nt)
#pragma unroll
            for (int r4 = 0; r4 < 4; ++r4) {
                const int row = m0 + wm * 64 + mt * 16 + quad * 4 + r4;
                const int col = n0 + wn * 64 + nt * 16 + l16;
                if (C_F32) ((float*)C_)[(size_t)row * N + col] = acc[mt][nt][r4];
                else       ((ushort*)C_)[(size_t)row * N + col] = f2bf(acc[mt][nt][r4]);
            }
}

// ---------- MFMA attention ----------
// Block = (b,h) 64x64 tile, 4 waves, wave w owns q rows [16w,16w+16).
// No Q/K/V LDS staging (each element read once; L2/L3-resident).
// QK: [tokens, 2048] bf16, Q at cols 0..1023 (h*64+d), K at cols 1024..2047.
// Vt: [1024, CROWS]  bf16, row f=h*64+d, col token.
// O overwrites the Q half in-place (safe: all Q/K reads complete before the
// P-repack __syncthreads; O region of block (b,h) read only by itself).
__global__ __launch_bounds__(256)
void attn_mfma(ushort* __restrict__ QK, const ushort* __restrict__ Vt,
               const float* __restrict__ bias, int CROWS) {
    const int t = threadIdx.x;
    const int lane = t & 63, wave = t >> 6;
    const int quad = lane >> 4, l16 = lane & 15;
    const int b = blockIdx.x >> 4, h = blockIdx.x & 15;
    const int SQK = 2048;
    const size_t qbase = (size_t)b * 64 * SQK + (size_t)h * 64;
    const size_t kbase = qbase + 1024;
    const size_t vbase = (size_t)(h * 64) * CROWS + (size_t)b * 64;

    __shared__ __attribute__((aligned(16))) ushort Pl[4 * 16 * 72];  // per-wave P[16][64], pad 72

    // ---- Q fragments: row=l16 (q within band), k(d)=ks*32+quad*8 ----
    bf16x8 qf[2];
#pragma unroll
    for (int ks = 0; ks < 2; ++ks)
        qf[ks] = *(const bf16x8*)&QK[qbase + (size_t)(wave * 16 + l16) * SQK + ks * 32 + quad * 8];

    // ---- S = Q K^T (contraction over d=64): M=16 q, N=64 kt ----
    const f32x4 zero = {0.f, 0.f, 0.f, 0.f};
    f32x4 s[4];
#pragma unroll
    for (int nt = 0; nt < 4; ++nt) s[nt] = zero;
#pragma unroll
    for (int nt = 0; nt < 4; ++nt)
#pragma unroll
        for (int ks = 0; ks < 2; ++ks) {
            bf16x8 kf = *(const bf16x8*)&QK[kbase + (size_t)(nt * 16 + l16) * SQK + ks * 32 + quad * 8];
            s[nt] = __builtin_amdgcn_mfma_f32_16x16x32_bf16(qf[ks], kf, s[nt], 0, 0, 0);
        }

    // ---- scale + bias; acc layout: row q = quad*4+r4 (+wave band), col kt = nt*16+l16 ----
    const int q0 = wave * 16 + quad * 4;
    float p[4][4];  // [nt][r4]
#pragma unroll
    for (int nt = 0; nt < 4; ++nt)
#pragma unroll
        for (int r4 = 0; r4 < 4; ++r4)
            p[nt][r4] = s[nt][r4] * 0.125f +
                        bias[(size_t)(h * 64 + q0 + r4) * 64 + nt * 16 + l16];

    // ---- row softmax: reduce over nt then across the 16 lanes of the quad ----
    float rinv[4];
#pragma unroll
    for (int r4 = 0; r4 < 4; ++r4) {
        float m = fmaxf(fmaxf(p[0][r4], p[1][r4]), fmaxf(p[2][r4], p[3][r4]));
        m = fmaxf(m, __shfl_xor(m, 1));
        m = fmaxf(m, __shfl_xor(m, 2));
        m = fmaxf(m, __shfl_xor(m, 4));
        m = fmaxf(m, __shfl_xor(m, 8));
#pragma unroll
        for (int nt = 0; nt < 4; ++nt) p[nt][r4] = __expf(p[nt][r4] - m);
        float sum = p[0][r4] + p[1][r4] + p[2][r4] + p[3][r4];
        sum += __shfl_xor(sum, 1);
        sum += __shfl_xor(sum, 2);
        sum += __shfl_xor(sum, 4);
        sum += __shfl_xor(sum, 8);
        rinv[r4] = 1.f / sum;
    }

    // ---- repack P to bf16 in LDS for the PV A-operand ----
#pragma unroll
    for (int nt = 0; nt < 4; ++nt)
#pragma unroll
        for (int r4 = 0; r4 < 4; ++r4)
            Pl[(wave * 16 + quad * 4 + r4) * 72 + nt * 16 + l16] = f2bf(p[nt][r4]);
    __syncthreads();

    // ---- O = P V (contraction over kt=64): M=16 q, N=64 d ----
    bf16x8 pa[2];
#pragma unroll
    for (int ks = 0; ks < 2; ++ks)
        pa[ks] = *(const bf16x8*)&Pl[(wave * 16 + l16) * 72 + ks * 32 + quad * 8];
    f32x4 o[4];
#pragma unroll
    for (int nt = 0; nt < 4; ++nt) o[nt] = zero;
#pragma unroll
    for (int nt = 0; nt < 4; ++nt)
#pragma unroll
        for (int ks = 0; ks < 2; ++ks) {
            bf16x8 vf = *(const bf16x8*)&Vt[vbase + (size_t)(nt * 16 + l16) * CROWS + ks * 32 + quad * 8];
            o[nt] = __builtin_amdgcn_mfma_f32_16x16x32_bf16(pa[ks], vf, o[nt], 0, 0, 0);
        }

    // ---- write O (deferred 1/l scaling) into Q half ----
#pragma unroll
    for (int nt = 0; nt < 4; ++nt)
#pragma unroll
        for (int r4 = 0; r4 < 4; ++r4)
            QK[qbase + (size_t)(q0 + r4) * SQK + nt * 16 + l16] = f2bf(o[nt][r4] * rinv[r4]);
}

extern "C" void kernel_launch(void* const* d_in, const int* in_sizes, int n_in,
                              void* d_out, int out_size, void* d_ws, size_t ws_size,
                              hipStream_t stream) {
    const float* x    = (const float*)d_in[0];   // [512,64,1024] f32
    const float* bias = (const float*)d_in[1];   // [1,16,64,64]  f32
    const float* Wq   = (const float*)d_in[2];
    const float* Wk   = (const float*)d_in[3];
    const float* Wv   = (const float*)d_in[4];
    const float* Wo   = (const float*)d_in[5];
    float* out = (float*)d_out;                  // [512,64,1024] f32

    const size_t D = 1024;
    const size_t WB = 4 * D * D * 2;             // 8.39 MB bf16 weights

    // ws-size-adaptive chunking: per chunk need CROWS*(2048+1024)*2 bytes after weights.
    int CHUNK_B = 128;                           // known-fit fallback (58.7 MB total)
    if (ws_size >= WB + (size_t)512 * 64 * 6144)      CHUNK_B = 512;
    else if (ws_size >= WB + (size_t)256 * 64 * 6144) CHUNK_B = 256;
    const int NCHUNK = 512 / CHUNK_B;
    const size_t CROWS = (size_t)CHUNK_B * 64;
    const size_t CELEM = CROWS * D;

    // ws layout: WqT|WkT (adjacent => fused [2048][1024]) | WvT | WoT | QKc | Vtc
    ushort* WqT = (ushort*)d_ws;
    ushort* WkT = WqT + D * D;
    ushort* WvT = WkT + D * D;
    ushort* WoT = WvT + D * D;
    ushort* QKc = WoT + D * D;                   // [CROWS][2048] bf16
    ushort* Vtc = QKc + CROWS * 2048;            // [1024][CROWS] bf16

    transpose1024<<<dim3(16, 16, 4), 256, 0, stream>>>(Wq, Wk, Wv, Wo, WqT, WkT, WvT, WoT);

    for (int c = 0; c < NCHUNK; ++c) {
        const float* xc = x + (size_t)c * CELEM;
        float* outc = out + (size_t)c * CELEM;
        ushort* Xc = (ushort*)outc;              // scratch: consumed before final GEMM writes
        cast_bf16<<<2048, 256, 0, stream>>>(xc, Xc, CELEM / 8);
        // fused Q|K projection: C[t][0..2047]
        gemm_bt<false><<<dim3(16, CROWS / 128), 256, 0, stream>>>(
            Xc, 1024, WqT, QKc, (int)CROWS, 2048, 1024);
        // transposed V projection: Vt[f][t] = sum_k WvT[f][k] * Xc[t][k]
        gemm_bt<false><<<dim3(CROWS / 128, 8), 256, 0, stream>>>(
            WvT, 1024, Xc, Vtc, 1024, (int)CROWS, 1024);
        // attention: O overwrites Q half of QKc
        attn_mfma<<<CHUNK_B * 16, 256, 0, stream>>>(QKc, Vtc, bias, (int)CROWS);
        // output projection: A = O (Q half, lda=2048)
        gemm_bt<true><<<dim3(8, CROWS / 128), 256, 0, stream>>>(
            QKc, 2048, WoT, outc, (int)CROWS, 1024, 1024);
    }
}

// Round 3
// 645.705 us; speedup vs baseline: 1.4010x; 1.1757x over previous
//
#include <hip/hip_runtime.h>
#include <hip/hip_bf16.h>
#include <stdint.h>

// ---------- bf16 helpers (raw ushort representation) ----------
__device__ inline float bf2f(ushort u) {
    union { uint32_t u; float f; } v; v.u = ((uint32_t)u) << 16; return v.f;
}
__device__ inline ushort f2bf(float f) {
    union { float f; uint32_t u; } v; v.f = f;
    uint32_t u = v.u;
    uint32_t r = (u + 0x7fffu + ((u >> 16) & 1u)) >> 16;  // RNE
    return (ushort)r;
}
__device__ inline uint32_t pk2bf(uint32_t flo, uint32_t fhi) {  // two f32 bit-patterns -> packed bf16x2
    uint32_t lo = (flo + 0x7fffu + ((flo >> 16) & 1u)) >> 16;
    uint32_t hi = (fhi + 0x7fffu + ((fhi >> 16) & 1u)) >> 16;
    return lo | (hi << 16);
}

typedef __attribute__((ext_vector_type(8))) short bf16x8;
typedef __attribute__((ext_vector_type(4))) float f32x4;

// async global->LDS, 16B per lane; LDS dest must be wave-uniform base (HW adds lane*16)
__device__ inline void gload_lds16(const ushort* g, ushort* l) {
    __builtin_amdgcn_global_load_lds(
        (const __attribute__((address_space(1))) void*)g,
        (__attribute__((address_space(3))) void*)l, 16, 0, 0);
}

// ---------- weight transpose+cast: W[1024,1024] f32 -> Wt[1024,1024] bf16 ----------
__global__ void transpose1024(const float* __restrict__ Wq, const float* __restrict__ Wk,
                              const float* __restrict__ Wv, const float* __restrict__ Wo,
                              ushort* __restrict__ WqT, ushort* __restrict__ WkT,
                              ushort* __restrict__ WvT, ushort* __restrict__ WoT) {
    const float* in; ushort* out;
    switch (blockIdx.z) {
        case 0: in = Wq; out = WqT; break;
        case 1: in = Wk; out = WkT; break;
        case 2: in = Wv; out = WvT; break;
        default: in = Wo; out = WoT; break;
    }
    __shared__ ushort tile[64][65];
    const int t = threadIdx.x;
    const int c = t & 63, rq = t >> 6;
    const int bx = blockIdx.x * 64, by = blockIdx.y * 64;
#pragma unroll
    for (int i = 0; i < 16; ++i) {
        int r = i * 4 + rq;
        tile[r][c] = f2bf(in[(size_t)(by + r) * 1024 + bx + c]);
    }
    __syncthreads();
#pragma unroll
    for (int i = 0; i < 16; ++i) {
        int r = i * 4 + rq;
        out[(size_t)(bx + r) * 1024 + by + c] = tile[c][r];
    }
}

// ---------- x chunk cast: f32 -> bf16, 8 elems/thread, grid-stride ----------
__global__ __launch_bounds__(256)
void cast_bf16(const float* __restrict__ in, ushort* __restrict__ out, size_t n8) {
    size_t i = (size_t)blockIdx.x * blockDim.x + threadIdx.x;
    const size_t stride = (size_t)gridDim.x * blockDim.x;
    for (; i < n8; i += stride) {
        const uint4 lo = *(const uint4*)&in[i * 8];
        const uint4 hi = *(const uint4*)&in[i * 8 + 4];
        uint4 o;
        o.x = pk2bf(lo.x, lo.y); o.y = pk2bf(lo.z, lo.w);
        o.z = pk2bf(hi.x, hi.y); o.w = pk2bf(hi.z, hi.w);
        *(uint4*)&out[i * 8] = o;
    }
}

// ---------- 256x256 8-phase bf16 GEMM: C[M,N] = A[M,K] @ Bt[N,K]^T ----------
// T3+T4 (8-phase counted vmcnt) + T5 (setprio) + T1 (bijective XCD swizzle).
// 8 waves (2Mx4N), BK=64, LDS 128 KiB = 2 buf x (A 32K + B 32K).
// Half-tiles split along K: per buffer regions (ushort offsets):
//   A-k0 @ 0, A-k1 @ 8192, B-k0 @ 16384, B-k1 @ 24576; each [256 rows][32 cols].
// Schedule per K-tile (ledger-verified):
//   P0: ds_read af[0-3][ks0]+bf[0-3][ks0]; stage next.A-k0; BAR; lgkm0; 16 MFMA; BAR
//   P1: ds_read af[4-7][ks0];              stage next.B-k0; BAR; lgkm0; 16 MFMA; vmcnt(4); BAR
//   P2: ds_read af[0-3][ks1]+bf[0-3][ks1]; stage next.A-k1; BAR; lgkm0; 16 MFMA; BAR
//   P3: ds_read af[4-7][ks1];              stage next.B-k1; BAR; lgkm0; 16 MFMA; vmcnt(4); BAR
// Steady state: 4-8 gload_lds in flight, vmcnt(4) retires exactly the two
// half-tiles the following two phases consume. Last tile: vmcnt(0) at P1, none at P3.
template <bool C_F32>
__global__ __launch_bounds__(512, 2)
void gemm256(const ushort* __restrict__ A, int lda, const ushort* __restrict__ Bt,
             void* __restrict__ C_, int M, int N, int K) {
    __shared__ __attribute__((aligned(16))) ushort lds[65536];  // 128 KiB
    const int t = threadIdx.x;
    const int lane = t & 63, wave = t >> 6;
    const int wm = wave >> 2, wn = wave & 3;       // 2 x 4 wave grid
    const int quad = lane >> 4, l16 = lane & 15;

    // bijective XCD swizzle (m204) on linear tile id
    const int gx = N >> 8;
    const int nwg = gridDim.x * gridDim.y;
    int wg = blockIdx.y * gridDim.x + blockIdx.x;
    {
        const int q = nwg >> 3, r = nwg & 7;
        const int xcd = wg & 7, loc = wg >> 3;
        wg = (xcd < r ? xcd * (q + 1) : r * (q + 1) + (xcd - r) * q) + loc;
    }
    const int m0 = (wg / gx) << 8, n0 = (wg % gx) << 8;

    const f32x4 zero = {0.f, 0.f, 0.f, 0.f};
    f32x4 acc[8][4];
#pragma unroll
    for (int i = 0; i < 8; ++i)
#pragma unroll
        for (int j = 0; j < 4; ++j) acc[i][j] = zero;

    // stage one 16 KB half-tile: 2 gload_lds per thread (1024 granules = 256 rows x 4)
    auto STAGE = [&](const ushort* __restrict__ src, int ldb, int rc0, int kcol,
                     int regio, int buf) {
        ushort* l = &lds[buf * 32768 + regio];
#pragma unroll
        for (int j = 0; j < 2; ++j) {
            const int g = j * 512 + t;
            const int r = g >> 2, cg = (g & 3) * 8;
            gload_lds16(&src[(size_t)(rc0 + r) * ldb + kcol + cg],
                        &l[(j * 512 + wave * 64) * 8]);
        }
    };

    const int NT = K >> 6;
    // ---- prologue: stage tile 0 (all 4 halves), retire A-k0/B-k0 ----
    STAGE(A, lda, m0, 0, 0, 0);
    STAGE(Bt, K, n0, 0, 16384, 0);
    STAGE(A, lda, m0, 32, 8192, 0);
    STAGE(Bt, K, n0, 32, 24576, 0);
    asm volatile("s_waitcnt vmcnt(4)" ::: "memory");
    __builtin_amdgcn_s_barrier();

    int cur = 0;
    for (int kt = 0; kt < NT; ++kt) {
        const bool nx = kt + 1 < NT;
        const int kn = (kt + 1) << 6;
        const ushort* la0 = &lds[cur * 32768];
        const ushort* lb0 = &lds[cur * 32768 + 16384];
        const ushort* la1 = la0 + 8192;
        const ushort* lb1 = lb0 + 8192;
        bf16x8 af[4], bf[4];

        // ================= P0: ks0, mt 0-3 =================
#pragma unroll
        for (int i = 0; i < 4; ++i) {
            af[i] = *(const bf16x8*)&la0[(wm * 128 + i * 16 + l16) * 32 + quad * 8];
            bf[i] = *(const bf16x8*)&lb0[(wn * 64 + i * 16 + l16) * 32 + quad * 8];
        }
        if (nx) STAGE(A, lda, m0, kn, 0, cur ^ 1);
        __builtin_amdgcn_sched_barrier(0);
        __builtin_amdgcn_s_barrier();
        asm volatile("s_waitcnt lgkmcnt(0)" ::: "memory");
        __builtin_amdgcn_sched_barrier(0);
        __builtin_amdgcn_s_setprio(1);
#pragma unroll
        for (int i = 0; i < 4; ++i)
#pragma unroll
            for (int n = 0; n < 4; ++n)
                acc[i][n] = __builtin_amdgcn_mfma_f32_16x16x32_bf16(af[i], bf[n], acc[i][n], 0, 0, 0);
        __builtin_amdgcn_s_setprio(0);
        __builtin_amdgcn_sched_barrier(0);
        __builtin_amdgcn_s_barrier();

        // ================= P1: ks0, mt 4-7 =================
#pragma unroll
        for (int i = 0; i < 4; ++i)
            af[i] = *(const bf16x8*)&la0[(wm * 128 + (i + 4) * 16 + l16) * 32 + quad * 8];
        if (nx) STAGE(Bt, K, n0, kn, 16384, cur ^ 1);
        __builtin_amdgcn_sched_barrier(0);
        __builtin_amdgcn_s_barrier();
        asm volatile("s_waitcnt lgkmcnt(0)" ::: "memory");
        __builtin_amdgcn_sched_barrier(0);
        __builtin_amdgcn_s_setprio(1);
#pragma unroll
        for (int i = 0; i < 4; ++i)
#pragma unroll
            for (int n = 0; n < 4; ++n)
                acc[i + 4][n] = __builtin_amdgcn_mfma_f32_16x16x32_bf16(af[i], bf[n], acc[i + 4][n], 0, 0, 0);
        __builtin_amdgcn_s_setprio(0);
        if (nx) asm volatile("s_waitcnt vmcnt(4)" ::: "memory");
        else    asm volatile("s_waitcnt vmcnt(0)" ::: "memory");
        __builtin_amdgcn_sched_barrier(0);
        __builtin_amdgcn_s_barrier();

        // ================= P2: ks1, mt 0-3 =================
#pragma unroll
        for (int i = 0; i < 4; ++i) {
            af[i] = *(const bf16x8*)&la1[(wm * 128 + i * 16 + l16) * 32 + quad * 8];
            bf[i] = *(const bf16x8*)&lb1[(wn * 64 + i * 16 + l16) * 32 + quad * 8];
        }
        if (nx) STAGE(A, lda, m0, kn + 32, 8192, cur ^ 1);
        __builtin_amdgcn_sched_barrier(0);
        __builtin_amdgcn_s_barrier();
        asm volatile("s_waitcnt lgkmcnt(0)" ::: "memory");
        __builtin_amdgcn_sched_barrier(0);
        __builtin_amdgcn_s_setprio(1);
#pragma unroll
        for (int i = 0; i < 4; ++i)
#pragma unroll
            for (int n = 0; n < 4; ++n)
                acc[i][n] = __builtin_amdgcn_mfma_f32_16x16x32_bf16(af[i], bf[n], acc[i][n], 0, 0, 0);
        __builtin_amdgcn_s_setprio(0);
        __builtin_amdgcn_sched_barrier(0);
        __builtin_amdgcn_s_barrier();

        // ================= P3: ks1, mt 4-7 =================
#pragma unroll
        for (int i = 0; i < 4; ++i)
            af[i] = *(const bf16x8*)&la1[(wm * 128 + (i + 4) * 16 + l16) * 32 + quad * 8];
        if (nx) STAGE(Bt, K, n0, kn + 32, 24576, cur ^ 1);
        __builtin_amdgcn_sched_barrier(0);
        __builtin_amdgcn_s_barrier();
        asm volatile("s_waitcnt lgkmcnt(0)" ::: "memory");
        __builtin_amdgcn_sched_barrier(0);
        __builtin_amdgcn_s_setprio(1);
#pragma unroll
        for (int i = 0; i < 4; ++i)
#pragma unroll
            for (int n = 0; n < 4; ++n)
                acc[i + 4][n] = __builtin_amdgcn_mfma_f32_16x16x32_bf16(af[i], bf[n], acc[i + 4][n], 0, 0, 0);
        __builtin_amdgcn_s_setprio(0);
        if (nx) asm volatile("s_waitcnt vmcnt(4)" ::: "memory");
        __builtin_amdgcn_sched_barrier(0);
        __builtin_amdgcn_s_barrier();

        cur ^= 1;
    }

    // ---- epilogue: C/D layout col = lane&15, row = quad*4 + reg ----
#pragma unroll
    for (int mt = 0; mt < 8; ++mt)
#pragma unroll
        for (int nt = 0; nt < 4; ++nt)
#pragma unroll
            for (int r4 = 0; r4 < 4; ++r4) {
                const int row = m0 + wm * 128 + mt * 16 + quad * 4 + r4;
                const int col = n0 + wn * 64 + nt * 16 + l16;
                if (C_F32) ((float*)C_)[(size_t)row * N + col] = acc[mt][nt][r4];
                else       ((ushort*)C_)[(size_t)row * N + col] = f2bf(acc[mt][nt][r4]);
            }
}

// ---------- MFMA attention ----------
// Block = (b,h) 64x64 tile, 4 waves, wave w owns q rows [16w,16w+16).
// No Q/K/V LDS staging (each element read once; L2/L3-resident).
// QK: [tokens, 2048] bf16, Q at cols 0..1023 (h*64+d), K at cols 1024..2047.
// Vt: [1024, CROWS]  bf16, row f=h*64+d, col token.
// O overwrites the Q half in-place (safe: all Q/K reads complete before the
// P-repack __syncthreads; O region of block (b,h) read only by itself).
__global__ __launch_bounds__(256)
void attn_mfma(ushort* __restrict__ QK, const ushort* __restrict__ Vt,
               const float* __restrict__ bias, int CROWS) {
    const int t = threadIdx.x;
    const int lane = t & 63, wave = t >> 6;
    const int quad = lane >> 4, l16 = lane & 15;
    const int b = blockIdx.x >> 4, h = blockIdx.x & 15;
    const int SQK = 2048;
    const size_t qbase = (size_t)b * 64 * SQK + (size_t)h * 64;
    const size_t kbase = qbase + 1024;
    const size_t vbase = (size_t)(h * 64) * CROWS + (size_t)b * 64;

    __shared__ __attribute__((aligned(16))) ushort Pl[4 * 16 * 72];  // per-wave P[16][64], pad 72

    // ---- Q fragments: row=l16 (q within band), k(d)=ks*32+quad*8 ----
    bf16x8 qf[2];
#pragma unroll
    for (int ks = 0; ks < 2; ++ks)
        qf[ks] = *(const bf16x8*)&QK[qbase + (size_t)(wave * 16 + l16) * SQK + ks * 32 + quad * 8];

    // ---- S = Q K^T (contraction over d=64): M=16 q, N=64 kt ----
    const f32x4 zero = {0.f, 0.f, 0.f, 0.f};
    f32x4 s[4];
#pragma unroll
    for (int nt = 0; nt < 4; ++nt) s[nt] = zero;
#pragma unroll
    for (int nt = 0; nt < 4; ++nt)
#pragma unroll
        for (int ks = 0; ks < 2; ++ks) {
            bf16x8 kf = *(const bf16x8*)&QK[kbase + (size_t)(nt * 16 + l16) * SQK + ks * 32 + quad * 8];
            s[nt] = __builtin_amdgcn_mfma_f32_16x16x32_bf16(qf[ks], kf, s[nt], 0, 0, 0);
        }

    // ---- scale + bias; acc layout: row q = quad*4+r4 (+wave band), col kt = nt*16+l16 ----
    const int q0 = wave * 16 + quad * 4;
    float p[4][4];  // [nt][r4]
#pragma unroll
    for (int nt = 0; nt < 4; ++nt)
#pragma unroll
        for (int r4 = 0; r4 < 4; ++r4)
            p[nt][r4] = s[nt][r4] * 0.125f +
                        bias[(size_t)(h * 64 + q0 + r4) * 64 + nt * 16 + l16];

    // ---- row softmax: reduce over nt then across the 16 lanes of the quad ----
    float rinv[4];
#pragma unroll
    for (int r4 = 0; r4 < 4; ++r4) {
        float m = fmaxf(fmaxf(p[0][r4], p[1][r4]), fmaxf(p[2][r4], p[3][r4]));
        m = fmaxf(m, __shfl_xor(m, 1));
        m = fmaxf(m, __shfl_xor(m, 2));
        m = fmaxf(m, __shfl_xor(m, 4));
        m = fmaxf(m, __shfl_xor(m, 8));
#pragma unroll
        for (int nt = 0; nt < 4; ++nt) p[nt][r4] = __expf(p[nt][r4] - m);
        float sum = p[0][r4] + p[1][r4] + p[2][r4] + p[3][r4];
        sum += __shfl_xor(sum, 1);
        sum += __shfl_xor(sum, 2);
        sum += __shfl_xor(sum, 4);
        sum += __shfl_xor(sum, 8);
        rinv[r4] = 1.f / sum;
    }

    // ---- repack P to bf16 in LDS for the PV A-operand ----
#pragma unroll
    for (int nt = 0; nt < 4; ++nt)
#pragma unroll
        for (int r4 = 0; r4 < 4; ++r4)
            Pl[(wave * 16 + quad * 4 + r4) * 72 + nt * 16 + l16] = f2bf(p[nt][r4]);
    __syncthreads();

    // ---- O = P V (contraction over kt=64): M=16 q, N=64 d ----
    bf16x8 pa[2];
#pragma unroll
    for (int ks = 0; ks < 2; ++ks)
        pa[ks] = *(const bf16x8*)&Pl[(wave * 16 + l16) * 72 + ks * 32 + quad * 8];
    f32x4 o[4];
#pragma unroll
    for (int nt = 0; nt < 4; ++nt) o[nt] = zero;
#pragma unroll
    for (int nt = 0; nt < 4; ++nt)
#pragma unroll
        for (int ks = 0; ks < 2; ++ks) {
            bf16x8 vf = *(const bf16x8*)&Vt[vbase + (size_t)(nt * 16 + l16) * CROWS + ks * 32 + quad * 8];
            o[nt] = __builtin_amdgcn_mfma_f32_16x16x32_bf16(pa[ks], vf, o[nt], 0, 0, 0);
        }

    // ---- write O (deferred 1/l scaling) into Q half ----
#pragma unroll
    for (int nt = 0; nt < 4; ++nt)
#pragma unroll
        for (int r4 = 0; r4 < 4; ++r4)
            QK[qbase + (size_t)(q0 + r4) * SQK + nt * 16 + l16] = f2bf(o[nt][r4] * rinv[r4]);
}

extern "C" void kernel_launch(void* const* d_in, const int* in_sizes, int n_in,
                              void* d_out, int out_size, void* d_ws, size_t ws_size,
                              hipStream_t stream) {
    const float* x    = (const float*)d_in[0];   // [512,64,1024] f32
    const float* bias = (const float*)d_in[1];   // [1,16,64,64]  f32
    const float* Wq   = (const float*)d_in[2];
    const float* Wk   = (const float*)d_in[3];
    const float* Wv   = (const float*)d_in[4];
    const float* Wo   = (const float*)d_in[5];
    float* out = (float*)d_out;                  // [512,64,1024] f32

    const size_t D = 1024;
    const size_t WB = 4 * D * D * 2;             // 8.39 MB bf16 weights

    // ws-size-adaptive chunking: per chunk need CROWS*(2048+1024)*2 bytes after weights.
    int CHUNK_B = 128;                           // known-fit fallback (58.7 MB total)
    if (ws_size >= WB + (size_t)512 * 64 * 6144)      CHUNK_B = 512;
    else if (ws_size >= WB + (size_t)256 * 64 * 6144) CHUNK_B = 256;
    const int NCHUNK = 512 / CHUNK_B;
    const size_t CROWS = (size_t)CHUNK_B * 64;
    const size_t CELEM = CROWS * D;

    // ws layout: WqT|WkT (adjacent => fused [2048][1024]) | WvT | WoT | QKc | Vtc
    ushort* WqT = (ushort*)d_ws;
    ushort* WkT = WqT + D * D;
    ushort* WvT = WkT + D * D;
    ushort* WoT = WvT + D * D;
    ushort* QKc = WoT + D * D;                   // [CROWS][2048] bf16
    ushort* Vtc = QKc + CROWS * 2048;            // [1024][CROWS] bf16

    transpose1024<<<dim3(16, 16, 4), 256, 0, stream>>>(Wq, Wk, Wv, Wo, WqT, WkT, WvT, WoT);

    for (int c = 0; c < NCHUNK; ++c) {
        const float* xc = x + (size_t)c * CELEM;
        float* outc = out + (size_t)c * CELEM;
        ushort* Xc = (ushort*)outc;              // scratch: consumed before final GEMM writes
        cast_bf16<<<2048, 256, 0, stream>>>(xc, Xc, CELEM / 8);
        // fused Q|K projection: C[t][0..2047]
        gemm256<false><<<dim3(8, CROWS / 256), 512, 0, stream>>>(
            Xc, 1024, WqT, QKc, (int)CROWS, 2048, 1024);
        // transposed V projection: Vt[f][t] = sum_k WvT[f][k] * Xc[t][k]
        gemm256<false><<<dim3(CROWS / 256, 4), 512, 0, stream>>>(
            WvT, 1024, Xc, Vtc, 1024, (int)CROWS, 1024);
        // attention: O overwrites Q half of QKc
        attn_mfma<<<CHUNK_B * 16, 256, 0, stream>>>(QKc, Vtc, bias, (int)CROWS);
        // output projection: A = O (Q half, lda=2048)
        gemm256<true><<<dim3(4, CROWS / 256), 512, 0, stream>>>(
            QKc, 2048, WoT, outc, (int)CROWS, 1024, 1024);
    }
}

// Round 4
// 613.640 us; speedup vs baseline: 1.4742x; 1.0523x over previous
//
#include <hip/hip_runtime.h>
#include <hip/hip_bf16.h>
#include <stdint.h>

// ---------- bf16 helpers (raw ushort representation) ----------
__device__ inline float bf2f(ushort u) {
    union { uint32_t u; float f; } v; v.u = ((uint32_t)u) << 16; return v.f;
}
__device__ inline ushort f2bf(float f) {
    union { float f; uint32_t u; } v; v.f = f;
    uint32_t u = v.u;
    uint32_t r = (u + 0x7fffu + ((u >> 16) & 1u)) >> 16;  // RNE
    return (ushort)r;
}
__device__ inline uint32_t pk2bf(uint32_t flo, uint32_t fhi) {  // two f32 bit-patterns -> packed bf16x2
    uint32_t lo = (flo + 0x7fffu + ((flo >> 16) & 1u)) >> 16;
    uint32_t hi = (fhi + 0x7fffu + ((fhi >> 16) & 1u)) >> 16;
    return lo | (hi << 16);
}

typedef __attribute__((ext_vector_type(8))) short bf16x8;
typedef __attribute__((ext_vector_type(4))) float f32x4;

// async global->LDS, 16B per lane; LDS dest must be wave-uniform base (HW adds lane*16)
__device__ inline void gload_lds16(const ushort* g, ushort* l) {
    __builtin_amdgcn_global_load_lds(
        (const __attribute__((address_space(1))) void*)g,
        (__attribute__((address_space(3))) void*)l, 16, 0, 0);
}

// ---------- weight transpose+cast: W[1024,1024] f32 -> Wt[1024,1024] bf16 ----------
__global__ void transpose1024(const float* __restrict__ Wq, const float* __restrict__ Wk,
                              const float* __restrict__ Wv, const float* __restrict__ Wo,
                              ushort* __restrict__ WqT, ushort* __restrict__ WkT,
                              ushort* __restrict__ WvT, ushort* __restrict__ WoT) {
    const float* in; ushort* out;
    switch (blockIdx.z) {
        case 0: in = Wq; out = WqT; break;
        case 1: in = Wk; out = WkT; break;
        case 2: in = Wv; out = WvT; break;
        default: in = Wo; out = WoT; break;
    }
    __shared__ ushort tile[64][65];
    const int t = threadIdx.x;
    const int c = t & 63, rq = t >> 6;
    const int bx = blockIdx.x * 64, by = blockIdx.y * 64;
#pragma unroll
    for (int i = 0; i < 16; ++i) {
        int r = i * 4 + rq;
        tile[r][c] = f2bf(in[(size_t)(by + r) * 1024 + bx + c]);
    }
    __syncthreads();
#pragma unroll
    for (int i = 0; i < 16; ++i) {
        int r = i * 4 + rq;
        out[(size_t)(bx + r) * 1024 + by + c] = tile[c][r];
    }
}

// ---------- x chunk cast: f32 -> bf16, 8 elems/thread, grid-stride ----------
__global__ __launch_bounds__(256)
void cast_bf16(const float* __restrict__ in, ushort* __restrict__ out, size_t n8) {
    size_t i = (size_t)blockIdx.x * blockDim.x + threadIdx.x;
    const size_t stride = (size_t)gridDim.x * blockDim.x;
    for (; i < n8; i += stride) {
        const uint4 lo = *(const uint4*)&in[i * 8];
        const uint4 hi = *(const uint4*)&in[i * 8 + 4];
        uint4 o;
        o.x = pk2bf(lo.x, lo.y); o.y = pk2bf(lo.z, lo.w);
        o.z = pk2bf(hi.x, hi.y); o.w = pk2bf(hi.z, hi.w);
        *(uint4*)&out[i * 8] = o;
    }
}

// ---------- 256x256 8-phase bf16 GEMM: C[M,N] = A[M,K] @ Bt[N,K]^T ----------
// T2 (granule XOR swizzle) + T3+T4 (8-phase counted vmcnt) + T5 (setprio) + T1 (XCD swizzle).
// 8 waves (2Mx4N), BK=64, LDS 128 KiB = 2 buf x (A 32K + B 32K).
// Half-tiles split along K: per buffer regions (ushort offsets):
//   A-k0 @ 0, A-k1 @ 8192, B-k0 @ 16384, B-k1 @ 24576; each [256 rows][32 cols].
// T2: row stride is 64 B = 16 banks -> unswizzled ds_read_b128 is 8-way conflicted
// (only (row&1)<<6 | granule<<4 varies mod 128B). Fix: physical 16B-granule
// index = logical ^ ((row>>1)&3). gload_lds writes linearly, so the SAME
// involution is applied to the per-lane GLOBAL source address (rule 21 / m173).
// For 16 consecutive rows, (row&1,(row>>1)&3) covers all 8 mod-128B spans
// exactly twice -> every span read by exactly 2 lanes -> 2-way = free (m136).
template <bool C_F32>
__global__ __launch_bounds__(512, 2)
void gemm256(const ushort* __restrict__ A, int lda, const ushort* __restrict__ Bt,
             void* __restrict__ C_, int M, int N, int K) {
    __shared__ __attribute__((aligned(16))) ushort lds[65536];  // 128 KiB
    const int t = threadIdx.x;
    const int lane = t & 63, wave = t >> 6;
    const int wm = wave >> 2, wn = wave & 3;       // 2 x 4 wave grid
    const int quad = lane >> 4, l16 = lane & 15;

    // bijective XCD swizzle (m204) on linear tile id
    const int gx = N >> 8;
    const int nwg = gridDim.x * gridDim.y;
    int wg = blockIdx.y * gridDim.x + blockIdx.x;
    {
        const int q = nwg >> 3, r = nwg & 7;
        const int xcd = wg & 7, loc = wg >> 3;
        wg = (xcd < r ? xcd * (q + 1) : r * (q + 1) + (xcd - r) * q) + loc;
    }
    const int m0 = (wg / gx) << 8, n0 = (wg % gx) << 8;

    const f32x4 zero = {0.f, 0.f, 0.f, 0.f};
    f32x4 acc[8][4];
#pragma unroll
    for (int i = 0; i < 8; ++i)
#pragma unroll
        for (int j = 0; j < 4; ++j) acc[i][j] = zero;

    // stage one 16 KB half-tile: 2 gload_lds per thread (1024 granules = 256 rows x 4)
    // T2: pre-swizzle the global source granule so linear LDS slot (row, gp)
    // holds logical granule gp ^ ((row>>1)&3).
    auto STAGE = [&](const ushort* __restrict__ src, int ldb, int rc0, int kcol,
                     int regio, int buf) {
        ushort* l = &lds[buf * 32768 + regio];
#pragma unroll
        for (int j = 0; j < 2; ++j) {
            const int g = j * 512 + t;
            const int r = g >> 2;
            const int cg = (((g & 3) ^ ((r >> 1) & 3)) * 8);
            gload_lds16(&src[(size_t)(rc0 + r) * ldb + kcol + cg],
                        &l[(j * 512 + wave * 64) * 8]);
        }
    };
    // swizzled ds_read offset for logical (row R, granule quad)
    auto LOFF = [&](int R) { return R * 32 + (quad ^ ((R >> 1) & 3)) * 8; };

    const int NT = K >> 6;
    // ---- prologue: stage tile 0 (all 4 halves), retire A-k0/B-k0 ----
    STAGE(A, lda, m0, 0, 0, 0);
    STAGE(Bt, K, n0, 0, 16384, 0);
    STAGE(A, lda, m0, 32, 8192, 0);
    STAGE(Bt, K, n0, 32, 24576, 0);
    asm volatile("s_waitcnt vmcnt(4)" ::: "memory");
    __builtin_amdgcn_s_barrier();

    int cur = 0;
    for (int kt = 0; kt < NT; ++kt) {
        const bool nx = kt + 1 < NT;
        const int kn = (kt + 1) << 6;
        const ushort* la0 = &lds[cur * 32768];
        const ushort* lb0 = &lds[cur * 32768 + 16384];
        const ushort* la1 = la0 + 8192;
        const ushort* lb1 = lb0 + 8192;
        bf16x8 af[4], bf[4];

        // ================= P0: ks0, mt 0-3 =================
#pragma unroll
        for (int i = 0; i < 4; ++i) {
            af[i] = *(const bf16x8*)&la0[LOFF(wm * 128 + i * 16 + l16)];
            bf[i] = *(const bf16x8*)&lb0[LOFF(wn * 64 + i * 16 + l16)];
        }
        if (nx) STAGE(A, lda, m0, kn, 0, cur ^ 1);
        __builtin_amdgcn_sched_barrier(0);
        __builtin_amdgcn_s_barrier();
        asm volatile("s_waitcnt lgkmcnt(0)" ::: "memory");
        __builtin_amdgcn_sched_barrier(0);
        __builtin_amdgcn_s_setprio(1);
#pragma unroll
        for (int i = 0; i < 4; ++i)
#pragma unroll
            for (int n = 0; n < 4; ++n)
                acc[i][n] = __builtin_amdgcn_mfma_f32_16x16x32_bf16(af[i], bf[n], acc[i][n], 0, 0, 0);
        __builtin_amdgcn_s_setprio(0);
        __builtin_amdgcn_sched_barrier(0);
        __builtin_amdgcn_s_barrier();

        // ================= P1: ks0, mt 4-7 =================
#pragma unroll
        for (int i = 0; i < 4; ++i)
            af[i] = *(const bf16x8*)&la0[LOFF(wm * 128 + (i + 4) * 16 + l16)];
        if (nx) STAGE(Bt, K, n0, kn, 16384, cur ^ 1);
        __builtin_amdgcn_sched_barrier(0);
        __builtin_amdgcn_s_barrier();
        asm volatile("s_waitcnt lgkmcnt(0)" ::: "memory");
        __builtin_amdgcn_sched_barrier(0);
        __builtin_amdgcn_s_setprio(1);
#pragma unroll
        for (int i = 0; i < 4; ++i)
#pragma unroll
            for (int n = 0; n < 4; ++n)
                acc[i + 4][n] = __builtin_amdgcn_mfma_f32_16x16x32_bf16(af[i], bf[n], acc[i + 4][n], 0, 0, 0);
        __builtin_amdgcn_s_setprio(0);
        if (nx) asm volatile("s_waitcnt vmcnt(4)" ::: "memory");
        else    asm volatile("s_waitcnt vmcnt(0)" ::: "memory");
        __builtin_amdgcn_sched_barrier(0);
        __builtin_amdgcn_s_barrier();

        // ================= P2: ks1, mt 0-3 =================
#pragma unroll
        for (int i = 0; i < 4; ++i) {
            af[i] = *(const bf16x8*)&la1[LOFF(wm * 128 + i * 16 + l16)];
            bf[i] = *(const bf16x8*)&lb1[LOFF(wn * 64 + i * 16 + l16)];
        }
        if (nx) STAGE(A, lda, m0, kn + 32, 8192, cur ^ 1);
        __builtin_amdgcn_sched_barrier(0);
        __builtin_amdgcn_s_barrier();
        asm volatile("s_waitcnt lgkmcnt(0)" ::: "memory");
        __builtin_amdgcn_sched_barrier(0);
        __builtin_amdgcn_s_setprio(1);
#pragma unroll
        for (int i = 0; i < 4; ++i)
#pragma unroll
            for (int n = 0; n < 4; ++n)
                acc[i][n] = __builtin_amdgcn_mfma_f32_16x16x32_bf16(af[i], bf[n], acc[i][n], 0, 0, 0);
        __builtin_amdgcn_s_setprio(0);
        __builtin_amdgcn_sched_barrier(0);
        __builtin_amdgcn_s_barrier();

        // ================= P3: ks1, mt 4-7 =================
#pragma unroll
        for (int i = 0; i < 4; ++i)
            af[i] = *(const bf16x8*)&la1[LOFF(wm * 128 + (i + 4) * 16 + l16)];
        if (nx) STAGE(Bt, K, n0, kn + 32, 24576, cur ^ 1);
        __builtin_amdgcn_sched_barrier(0);
        __builtin_amdgcn_s_barrier();
        asm volatile("s_waitcnt lgkmcnt(0)" ::: "memory");
        __builtin_amdgcn_sched_barrier(0);
        __builtin_amdgcn_s_setprio(1);
#pragma unroll
        for (int i = 0; i < 4; ++i)
#pragma unroll
            for (int n = 0; n < 4; ++n)
                acc[i + 4][n] = __builtin_amdgcn_mfma_f32_16x16x32_bf16(af[i], bf[n], acc[i + 4][n], 0, 0, 0);
        __builtin_amdgcn_s_setprio(0);
        if (nx) asm volatile("s_waitcnt vmcnt(4)" ::: "memory");
        __builtin_amdgcn_sched_barrier(0);
        __builtin_amdgcn_s_barrier();

        cur ^= 1;
    }

    // ---- epilogue: C/D layout col = lane&15, row = quad*4 + reg ----
#pragma unroll
    for (int mt = 0; mt < 8; ++mt)
#pragma unroll
        for (int nt = 0; nt < 4; ++nt)
#pragma unroll
            for (int r4 = 0; r4 < 4; ++r4) {
                const int row = m0 + wm * 128 + mt * 16 + quad * 4 + r4;
                const int col = n0 + wn * 64 + nt * 16 + l16;
                if (C_F32) ((float*)C_)[(size_t)row * N + col] = acc[mt][nt][r4];
                else       ((ushort*)C_)[(size_t)row * N + col] = f2bf(acc[mt][nt][r4]);
            }
}

// ---------- MFMA attention ----------
// Block = (b,h) 64x64 tile, 4 waves, wave w owns q rows [16w,16w+16).
// No Q/K/V LDS staging (each element read once; L2/L3-resident).
// QK: [tokens, 2048] bf16, Q at cols 0..1023 (h*64+d), K at cols 1024..2047.
// Vt: [1024, CROWS]  bf16, row f=h*64+d, col token.
// O overwrites the Q half in-place (safe: all Q/K reads complete before the
// P-repack __syncthreads; O region of block (b,h) read only by itself).
__global__ __launch_bounds__(256)
void attn_mfma(ushort* __restrict__ QK, const ushort* __restrict__ Vt,
               const float* __restrict__ bias, int CROWS) {
    const int t = threadIdx.x;
    const int lane = t & 63, wave = t >> 6;
    const int quad = lane >> 4, l16 = lane & 15;
    const int b = blockIdx.x >> 4, h = blockIdx.x & 15;
    const int SQK = 2048;
    const size_t qbase = (size_t)b * 64 * SQK + (size_t)h * 64;
    const size_t kbase = qbase + 1024;
    const size_t vbase = (size_t)(h * 64) * CROWS + (size_t)b * 64;

    __shared__ __attribute__((aligned(16))) ushort Pl[4 * 16 * 72];  // per-wave P[16][64], pad 72

    // ---- Q fragments: row=l16 (q within band), k(d)=ks*32+quad*8 ----
    bf16x8 qf[2];
#pragma unroll
    for (int ks = 0; ks < 2; ++ks)
        qf[ks] = *(const bf16x8*)&QK[qbase + (size_t)(wave * 16 + l16) * SQK + ks * 32 + quad * 8];

    // ---- S = Q K^T (contraction over d=64): M=16 q, N=64 kt ----
    const f32x4 zero = {0.f, 0.f, 0.f, 0.f};
    f32x4 s[4];
#pragma unroll
    for (int nt = 0; nt < 4; ++nt) s[nt] = zero;
#pragma unroll
    for (int nt = 0; nt < 4; ++nt)
#pragma unroll
        for (int ks = 0; ks < 2; ++ks) {
            bf16x8 kf = *(const bf16x8*)&QK[kbase + (size_t)(nt * 16 + l16) * SQK + ks * 32 + quad * 8];
            s[nt] = __builtin_amdgcn_mfma_f32_16x16x32_bf16(qf[ks], kf, s[nt], 0, 0, 0);
        }

    // ---- scale + bias; acc layout: row q = quad*4+r4 (+wave band), col kt = nt*16+l16 ----
    const int q0 = wave * 16 + quad * 4;
    float p[4][4];  // [nt][r4]
#pragma unroll
    for (int nt = 0; nt < 4; ++nt)
#pragma unroll
        for (int r4 = 0; r4 < 4; ++r4)
            p[nt][r4] = s[nt][r4] * 0.125f +
                        bias[(size_t)(h * 64 + q0 + r4) * 64 + nt * 16 + l16];

    // ---- row softmax: reduce over nt then across the 16 lanes of the quad ----
    float rinv[4];
#pragma unroll
    for (int r4 = 0; r4 < 4; ++r4) {
        float m = fmaxf(fmaxf(p[0][r4], p[1][r4]), fmaxf(p[2][r4], p[3][r4]));
        m = fmaxf(m, __shfl_xor(m, 1));
        m = fmaxf(m, __shfl_xor(m, 2));
        m = fmaxf(m, __shfl_xor(m, 4));
        m = fmaxf(m, __shfl_xor(m, 8));
#pragma unroll
        for (int nt = 0; nt < 4; ++nt) p[nt][r4] = __expf(p[nt][r4] - m);
        float sum = p[0][r4] + p[1][r4] + p[2][r4] + p[3][r4];
        sum += __shfl_xor(sum, 1);
        sum += __shfl_xor(sum, 2);
        sum += __shfl_xor(sum, 4);
        sum += __shfl_xor(sum, 8);
        rinv[r4] = 1.f / sum;
    }

    // ---- repack P to bf16 in LDS for the PV A-operand ----
#pragma unroll
    for (int nt = 0; nt < 4; ++nt)
#pragma unroll
        for (int r4 = 0; r4 < 4; ++r4)
            Pl[(wave * 16 + quad * 4 + r4) * 72 + nt * 16 + l16] = f2bf(p[nt][r4]);
    __syncthreads();

    // ---- O = P V (contraction over kt=64): M=16 q, N=64 d ----
    bf16x8 pa[2];
#pragma unroll
    for (int ks = 0; ks < 2; ++ks)
        pa[ks] = *(const bf16x8*)&Pl[(wave * 16 + l16) * 72 + ks * 32 + quad * 8];
    f32x4 o[4];
#pragma unroll
    for (int nt = 0; nt < 4; ++nt) o[nt] = zero;
#pragma unroll
    for (int nt = 0; nt < 4; ++nt)
#pragma unroll
        for (int ks = 0; ks < 2; ++ks) {
            bf16x8 vf = *(const bf16x8*)&Vt[vbase + (size_t)(nt * 16 + l16) * CROWS + ks * 32 + quad * 8];
            o[nt] = __builtin_amdgcn_mfma_f32_16x16x32_bf16(pa[ks], vf, o[nt], 0, 0, 0);
        }

    // ---- write O (deferred 1/l scaling) into Q half ----
#pragma unroll
    for (int nt = 0; nt < 4; ++nt)
#pragma unroll
        for (int r4 = 0; r4 < 4; ++r4)
            QK[qbase + (size_t)(q0 + r4) * SQK + nt * 16 + l16] = f2bf(o[nt][r4] * rinv[r4]);
}

extern "C" void kernel_launch(void* const* d_in, const int* in_sizes, int n_in,
                              void* d_out, int out_size, void* d_ws, size_t ws_size,
                              hipStream_t stream) {
    const float* x    = (const float*)d_in[0];   // [512,64,1024] f32
    const float* bias = (const float*)d_in[1];   // [1,16,64,64]  f32
    const float* Wq   = (const float*)d_in[2];
    const float* Wk   = (const float*)d_in[3];
    const float* Wv   = (const float*)d_in[4];
    const float* Wo   = (const float*)d_in[5];
    float* out = (float*)d_out;                  // [512,64,1024] f32

    const size_t D = 1024;
    const size_t WB = 4 * D * D * 2;             // 8.39 MB bf16 weights

    // ws-size-adaptive chunking: per chunk need CROWS*(2048+1024)*2 bytes after weights.
    int CHUNK_B = 128;                           // known-fit fallback (58.7 MB total)
    if (ws_size >= WB + (size_t)512 * 64 * 6144)      CHUNK_B = 512;
    else if (ws_size >= WB + (size_t)256 * 64 * 6144) CHUNK_B = 256;
    const int NCHUNK = 512 / CHUNK_B;
    const size_t CROWS = (size_t)CHUNK_B * 64;
    const size_t CELEM = CROWS * D;

    // ws layout: WqT|WkT (adjacent => fused [2048][1024]) | WvT | WoT | QKc | Vtc
    ushort* WqT = (ushort*)d_ws;
    ushort* WkT = WqT + D * D;
    ushort* WvT = WkT + D * D;
    ushort* WoT = WvT + D * D;
    ushort* QKc = WoT + D * D;                   // [CROWS][2048] bf16
    ushort* Vtc = QKc + CROWS * 2048;            // [1024][CROWS] bf16

    transpose1024<<<dim3(16, 16, 4), 256, 0, stream>>>(Wq, Wk, Wv, Wo, WqT, WkT, WvT, WoT);

    for (int c = 0; c < NCHUNK; ++c) {
        const float* xc = x + (size_t)c * CELEM;
        float* outc = out + (size_t)c * CELEM;
        ushort* Xc = (ushort*)outc;              // scratch: consumed before final GEMM writes
        cast_bf16<<<2048, 256, 0, stream>>>(xc, Xc, CELEM / 8);
        // fused Q|K projection: C[t][0..2047]
        gemm256<false><<<dim3(8, CROWS / 256), 512, 0, stream>>>(
            Xc, 1024, WqT, QKc, (int)CROWS, 2048, 1024);
        // transposed V projection: Vt[f][t] = sum_k WvT[f][k] * Xc[t][k]
        gemm256<false><<<dim3(CROWS / 256, 4), 512, 0, stream>>>(
            WvT, 1024, Xc, Vtc, 1024, (int)CROWS, 1024);
        // attention: O overwrites Q half of QKc
        attn_mfma<<<CHUNK_B * 16, 256, 0, stream>>>(QKc, Vtc, bias, (int)CROWS);
        // output projection: A = O (Q half, lda=2048)
        gemm256<true><<<dim3(4, CROWS / 256), 512, 0, stream>>>(
            QKc, 2048, WoT, outc, (int)CROWS, 1024, 1024);
    }
}